// Round 17
// baseline (481.802 us; speedup 1.0000x reference)
//
#include <hip/hip_runtime.h>

typedef unsigned short u16;
typedef unsigned int u32;
typedef unsigned long long u64;
typedef __attribute__((ext_vector_type(4))) int i32x4;
typedef __attribute__((ext_vector_type(16))) int i32x16;

#define TT 16
#define Z16 {0, 0, 0, 0, 0, 0, 0, 0, 0, 0, 0, 0, 0, 0, 0, 0}

// ---------------------------------------------------------------------------
// f64 LIF scan (soft reset, THETA=1). R2..R16: absmax=0.0 => order-free,
// margins >> f64 noise.
// ---------------------------------------------------------------------------
__device__ __forceinline__ u32 scan_spike(const double* acc) {
  double u = 0.0;
  u32 m = 0;
#pragma unroll
  for (int t = 0; t < TT; ++t) {
    u += acc[t];
    if (u >= 1.0) { m |= (1u << t); u -= 1.0; }
  }
  return m;
}

__device__ __forceinline__ long long shfl_xor64(long long v, int m) {
  int lo = __shfl_xor((int)(v & 0xffffffffLL), m);
  int hi = __shfl_xor((int)(v >> 32), m);
  return ((long long)hi << 32) | (u32)lo;
}

// ---------------------------------------------------------------------------
// Layer 1: conv3x3 pad1 Cin=1.
// R28: quarter-split occupancy fix. The R14 persistent form launched 256
// blocks = exactly 1 block/CU (7 waves = 22% occupancy cap) -- latency-
// bound by construction. Now grid 512: block = (n, quarter), tiles 4/3/4/3
// -> 2 blocks/CU, 14 waves/CU. Each output still computed entirely in one
// block with identical f32-conv + f64-scan expressions in identical order
// => bit-identical s1/T1f. Fused T1f interior write kept (R27).
// ---------------------------------------------------------------------------
__device__ __forceinline__ float conv1_fetch(const float* __restrict__ xn,
                                             int y0, int r, int col, int t) {
  int yi = y0 - 1 + r, xi = col - 1;
  if ((unsigned)yi < 28u && (unsigned)xi < 28u)
    return xn[((size_t)(yi * 28 + xi)) * 16 + t];
  return 0.0f;
}

__global__ __launch_bounds__(448) void conv1_lds(
    const float* __restrict__ x, const float* __restrict__ w,
    const float* __restrict__ b, u16* __restrict__ out,
    signed char* __restrict__ T1f) {
  __shared__ float xt[2][4][30][20];
  __shared__ float wl[32][9];

  int blk = blockIdx.x;  // 512: (n, quarter)
  int n = blk >> 2;
  int q = blk & 3;
  int ypBase = (q == 0) ? 0 : (q == 1) ? 4 : (q == 2) ? 7 : 11;
  int cnt = (q & 1) ? 3 : 4;
  int tid = threadIdx.x;

  for (int i = tid; i < 288; i += 448) wl[i / 9][i % 9] = w[i];

  // per-thread staging slots (4*30*16 = 1920 values, 448 threads, <=5 each)
  int sr_[5], sc_[5], st_[5];
  bool sok[5];
#pragma unroll
  for (int k = 0; k < 5; ++k) {
    int i = tid + k * 448;
    sok[k] = (i < 1920);
    int ii = sok[k] ? i : 0;
    sr_[k] = ii / 480;
    int rem = ii % 480;
    sc_[k] = rem / 16;
    st_[k] = rem % 16;
  }
  const float* xn = x + (size_t)n * (28 * 28 * 16);

  // thread map: ocg fastest for coalesced mask stores
  int ocg = tid & 7;
  int xx = (tid >> 3) % 28;
  int dy = tid / 224;  // 0 or 1
  int oc0 = ocg * 4;

  // prologue: stage tile 0 into buf 0
  {
    int y0 = ypBase * 2;
#pragma unroll
    for (int k = 0; k < 5; ++k)
      if (sok[k])
        xt[0][sr_[k]][sc_[k]][st_[k]] =
            conv1_fetch(xn, y0, sr_[k], sc_[k], st_[k]);
  }
  __syncthreads();

  float wr[4][9];
#pragma unroll
  for (int j = 0; j < 4; ++j)
#pragma unroll
    for (int ko = 0; ko < 9; ++ko) wr[j][ko] = wl[oc0 + j][ko];
  float bf[4];
#pragma unroll
  for (int j = 0; j < 4; ++j) bf[j] = b[oc0 + j];

  for (int it = 0; it < cnt; ++it) {
    int y0 = (ypBase + it) * 2;
    int cur = it & 1;

    // prefetch next tile into regs (latency hides under compute below)
    float pf[5];
    if (it + 1 < cnt) {
      int y0n = y0 + 2;
#pragma unroll
      for (int k = 0; k < 5; ++k)
        pf[k] = sok[k] ? conv1_fetch(xn, y0n, sr_[k], sc_[k], st_[k]) : 0.0f;
    }

    double u[4] = {0.0, 0.0, 0.0, 0.0};
    u32 m[4] = {0u, 0u, 0u, 0u};

    const float* row0 = &xt[cur][dy + 0][xx][0];
    const float* row1 = &xt[cur][dy + 1][xx][0];
    const float* row2 = &xt[cur][dy + 2][xx][0];

#pragma unroll
    for (int qq = 0; qq < 4; ++qq) {
      float4 xq[9];
#pragma unroll
      for (int kx = 0; kx < 3; ++kx) {
        xq[0 * 3 + kx] = *(const float4*)(row0 + kx * 20 + qq * 4);
        xq[1 * 3 + kx] = *(const float4*)(row1 + kx * 20 + qq * 4);
        xq[2 * 3 + kx] = *(const float4*)(row2 + kx * 20 + qq * 4);
      }
#pragma unroll
      for (int j = 0; j < 4; ++j) {
        float4 s = {0.0f, 0.0f, 0.0f, 0.0f};
#pragma unroll
        for (int ko = 0; ko < 9; ++ko) {
          s.x = fmaf(wr[j][ko], xq[ko].x, s.x);
          s.y = fmaf(wr[j][ko], xq[ko].y, s.y);
          s.z = fmaf(wr[j][ko], xq[ko].z, s.z);
          s.w = fmaf(wr[j][ko], xq[ko].w, s.w);
        }
        float y0f = s.x + bf[j], y1f = s.y + bf[j];
        float y2f = s.z + bf[j], y3f = s.w + bf[j];
        u[j] += (double)y0f;
        if (u[j] >= 1.0) { m[j] |= 1u << (4 * qq + 0); u[j] -= 1.0; }
        u[j] += (double)y1f;
        if (u[j] >= 1.0) { m[j] |= 1u << (4 * qq + 1); u[j] -= 1.0; }
        u[j] += (double)y2f;
        if (u[j] >= 1.0) { m[j] |= 1u << (4 * qq + 2); u[j] -= 1.0; }
        u[j] += (double)y3f;
        if (u[j] >= 1.0) { m[j] |= 1u << (4 * qq + 3); u[j] -= 1.0; }
      }
    }

    // coalesced 8B mask store: s1[n][y][x][32c]
    int yo = y0 + dy;
    u64 pk = (u64)(u16)m[0] | ((u64)(u16)m[1] << 16) |
             ((u64)(u16)m[2] << 32) | ((u64)(u16)m[3] << 48);
    *(u64*)(out + ((size_t)(n * 28 + yo) * 28 + xx) * 32 + oc0) = pk;

    // fused T1f interior write (replaces expand_masks)
    {
      signed char* Tp =
          T1f + (((size_t)n * 30 + yo + 1) * 30 + (xx + 1)) * 512 + oc0;
#pragma unroll
      for (int t = 0; t < TT; ++t) {
        u32 val = ((m[0] >> t) & 1u) | (((m[1] >> t) & 1u) << 8) |
                  (((m[2] >> t) & 1u) << 16) | (((m[3] >> t) & 1u) << 24);
        *(u32*)(Tp + t * 32) = val;
      }
    }

    if (it + 1 < cnt) {
      int nb = (it + 1) & 1;
#pragma unroll
      for (int k = 0; k < 5; ++k)
        if (sok[k]) xt[nb][sr_[k]][sc_[k]][st_[k]] = pf[k];
      __syncthreads();
    }
  }
}

// ---------------------------------------------------------------------------
// Digit prep in MFMA B-frag order for the 32ch 3x3 convs.
// 4 planes at scale 2^29 (R16 numerics; absmax=0.0 held through R5-R16).
// w2+w3 in one launch, grid 18.
// ---------------------------------------------------------------------------
__global__ void prep_digits_frag2(const float* __restrict__ wa,
                                  const float* __restrict__ wb,
                                  signed char* __restrict__ Wda,
                                  signed char* __restrict__ Wdb) {
  int bid = blockIdx.x;  // 18
  const float* w = (bid < 9) ? wa : wb;
  signed char* Wd = (bid < 9) ? Wda : Wdb;
  int tap = bid % 9;
  int lane = threadIdx.x;  // 64
  int oc = lane & 31, kh = lane >> 5;
  for (int j = 0; j < 16; ++j) {
    int c = kh * 16 + j;
    double xv = ldexp((double)w[((size_t)(oc * 32 + c)) * 9 + tap], 29);
    long long X = (long long)rint(xv);
    for (int p = 0; p < 4; ++p) {
      int d = (int)((X + 128) & 255) - 128;
      Wd[((size_t)((p * 9 + tap) * 64 + lane)) * 16 + j] = (signed char)d;
      X = (X - (long long)d) >> 8;
    }
  }
}

// ---------------------------------------------------------------------------
// L6 digit prep for conv_i8<14,14,16,16>: 4 planes at 2^29, oc>=16 and
// c>=16 get zero digits (N/K zero-padding).
// ---------------------------------------------------------------------------
__global__ void prep_digits5c(const float* __restrict__ w,
                              signed char* __restrict__ Wd) {
  int tap = blockIdx.x;    // 9
  int lane = threadIdx.x;  // 64
  int oc = lane & 31, kh = lane >> 5;
  for (int j = 0; j < 16; ++j) {
    long long X = 0;
    if (oc < 16 && kh == 0) {  // c = j < 16 real
      double xv = ldexp((double)w[((size_t)(oc * 16 + j)) * 9 + tap], 29);
      X = (long long)rint(xv);
    }
    for (int p = 0; p < 4; ++p) {
      int d = (int)((X + 128) & 255) - 128;
      Wd[((size_t)((p * 9 + tap) * 64 + lane)) * 16 + j] = (signed char)d;
      X = (X - (long long)d) >> 8;
    }
  }
}

// ---------------------------------------------------------------------------
// Zero only the border sites of full-batch T1f/T2f (x or y in {0,29});
// interiors are fully rewritten (proven R4-R11). 2x7.6 MB instead of 118 MB.
// ---------------------------------------------------------------------------
__global__ __launch_bounds__(256) void zero_borders(
    signed char* __restrict__ T1, signed char* __restrict__ T2) {
  const int PER = 128 * 116 * 32;  // 16B-chunks per buffer
  int idx = blockIdx.x * 256 + threadIdx.x;
  int buf = idx >= PER;
  int r = buf ? idx - PER : idx;
  if (r >= PER) return;
  int c16 = r & 31;
  int site = (r >> 5) % 116;
  int nloc = (r >> 5) / 116;
  int y, x;
  if (site < 30) { y = 0; x = site; }
  else if (site < 60) { y = 29; x = site - 30; }
  else if (site < 88) { x = 0; y = site - 60 + 1; }
  else { x = 29; y = site - 88 + 1; }
  signed char* T = buf ? T2 : T1;
  *(i32x4*)(T + (((size_t)nloc * 30 + y) * 30 + x) * 512 + c16 * 16) =
      (i32x4){0, 0, 0, 0};
}

// ---------------------------------------------------------------------------
// Expand s5 masks (16 ch) -> T5c[n][16][16][16t][32c] in conv_i8 T-format:
// lower 16 c from the proven 32x32 bit-transpose, upper 16 c zeroed by the
// same store. Borders pre-zeroed by memset.
// ---------------------------------------------------------------------------
__global__ __launch_bounds__(256) void expand_t5c(
    const u16* __restrict__ s, signed char* __restrict__ T) {
  int site = blockIdx.x * 8 + (threadIdx.x >> 5);  // 128*14*14
  int gl = threadIdx.x & 31;
  int x = site % 14; int t1 = site / 14;
  int y = t1 % 14;   int n = t1 / 14;

  u32 v = 0;
  if (gl < 16) v = (u32)s[(((size_t)n * 16 + gl) * 14 + y) * 14 + x];
  const u32 MK[5] = {0x0000FFFFu, 0x00FF00FFu, 0x0F0F0F0Fu,
                     0x33333333u, 0x55555555u};
#pragma unroll
  for (int i = 0; i < 5; ++i) {
    int sh = 16 >> i;
    u32 mk = MK[i];
    u32 p = (u32)__shfl_xor((int)v, sh);
    v = ((gl & sh) == 0) ? ((v & mk) | ((p & mk) << sh))
                         : ((v & ~mk) | ((p & ~mk) >> sh));
  }
  if (gl < 16) {
    u32 dw[4];
#pragma unroll
    for (int d = 0; d < 4; ++d) {
      u32 nib = (v >> (4 * d)) & 0xFu;
      dw[d] = (nib * 0x00204081u) & 0x01010101u;
    }
    signed char* Tp =
        T + ((((size_t)n * 16 + y + 1) * 16 + (x + 1))) * 512 + gl * 32;
    *(i32x4*)Tp = (i32x4){(int)dw[0], (int)dw[1], (int)dw[2], (int)dw[3]};
    *(i32x4*)(Tp + 16) = (i32x4){0, 0, 0, 0};  // upper 16 channels zero
  }
}

// ---------------------------------------------------------------------------
// Integer epilogue for 32x32 i8 MFMA C-layout (R4 algebra; scale 2^29).
// Residual gather uses s1's [n][y][x][c] layout (coalesced).
// ---------------------------------------------------------------------------
template <int H, int W, int PADW, int COUT, bool WRITE_T, bool HAS_RES>
__device__ __forceinline__ void epi_i8(long long (&cc)[16], int h, int oc,
                                       int px_out, int y, int nloc, int n_g,
                                       const float* bias,
                                       const u16* __restrict__ res,
                                       signed char* __restrict__ Tout,
                                       u16* __restrict__ mout) {
  long long recv[8];
#pragma unroll
  for (int j = 0; j < 8; ++j) {
    long long send = h ? cc[j] : cc[8 + j];
    recv[j] = shfl_xor64(send, 32);
  }
  long long B29 = 0;
  if (oc < COUT) B29 = (long long)rint((double)bias[oc] * 536870912.0);
  u32 rm = 0;
  if (HAS_RES && px_out < W)
    rm = res[(((size_t)n_g * H + y) * W + px_out) * COUT + oc];
  long long u = 0;
  u32 mo = 0;
  const long long TH = 1LL << 29;
#pragma unroll
  for (int t = 0; t < TT; ++t) {
    int lo = (t & 3) + 4 * (t >> 3);
    int sel = (t >> 2) & 1;
    long long own = h ? cc[8 + lo] : cc[lo];
    long long ut = (sel ^ h) ? recv[lo] : own;
    ut += B29 + (((rm >> t) & 1u) ? TH : 0);
    u += ut;
    if (u >= TH) { mo |= (1u << t); u -= TH; }
  }
  if (px_out < W && oc < COUT) {
    if (WRITE_T) {
      signed char* Tp =
          Tout + (((size_t)nloc * PADW + y + 1) * PADW + px_out + 1) * 512 + oc;
#pragma unroll
      for (int t = 0; t < TT; ++t)
        Tp[t * 32] = (signed char)((mo >> t) & 1u);
    } else {
      mout[(((size_t)n_g * COUT + oc) * H + y) * W + px_out] = (u16)mo;
    }
  }
}

// ---------------------------------------------------------------------------
// conv3x3 via i8 32x32x32 MFMA, 4 digit planes at 2^29.
// R25-proven one-tile-per-thread, 512-thread form (R15/R16: ~93-96us,
// VGPR 56, Occ ~34%, clean traffic). 8 waves/block each owning ONE 2-px
// tile. Retired levers: min-occ>=3 bounds (spills R6/R8); persistent
// blocks (L2 thrash R10/R11).
// ---------------------------------------------------------------------------
template <int H, int W, int PADW, int COUT, bool WRITE_T, bool HAS_RES>
__global__ __launch_bounds__(512, 2) void conv_i8(
    const signed char* __restrict__ Tin, const signed char* __restrict__ Wd,
    const float* __restrict__ bias, const u16* __restrict__ res,
    signed char* __restrict__ Tout, u16* __restrict__ mout, int nbase) {
  constexpr int TILESX = (W + 15) / 16;
  __shared__ signed char WL[4 * 9 * 1024];
  int tid = threadIdx.x;
  for (int j = tid; j < 2304; j += 512)
    ((i32x4*)WL)[j] = ((const i32x4*)Wd)[j];
  __syncthreads();

  int blk = blockIdx.x;
  int xblk = blk % TILESX; int b2 = blk / TILESX;
  int y = b2 % H;          int nloc = b2 / H;
  int lane = tid & 63, wid = tid >> 6;  // wid 0..7
  int h = lane >> 5, rowlane = lane & 31;
  int pxr = rowlane >> 4, tA = rowlane & 15;
  int wtile = wid >> 1, sel = wid & 1;
  int pxb = xblk * 16 + wtile * 4 + sel * 2;  // wave's 2-px tile base

  i32x4 A[9];
  const signed char* Tn = Tin + (size_t)nloc * (PADW * PADW * 512);
#pragma unroll
  for (int ky = 0; ky < 3; ++ky)
#pragma unroll
    for (int kx = 0; kx < 3; ++kx) {
      int tap = ky * 3 + kx;
      int ypad = y + ky;
      int x0 = pxb + pxr + kx;
      if (x0 > PADW - 1) x0 = PADW - 1;
      A[tap] = *(const i32x4*)(Tn + ((size_t)(ypad * PADW + x0)) * 512 +
                               tA * 32 + h * 16);
    }

  i32x16 cp[2];
#pragma unroll
  for (int pp = 0; pp < 2; ++pp) {
    i32x16 alo = Z16, ahi = Z16;
#pragma unroll
    for (int tap = 0; tap < 9; ++tap) {
      i32x4 Blo =
          *(const i32x4*)&WL[((size_t)(((2 * pp) * 9 + tap) * 64 + lane)) * 16];
      i32x4 Bhi = *(const i32x4*)&WL[((size_t)(((2 * pp + 1) * 9 + tap) * 64 +
                                               lane)) * 16];
      alo = __builtin_amdgcn_mfma_i32_32x32x32_i8(A[tap], Blo, alo, 0, 0, 0);
      ahi = __builtin_amdgcn_mfma_i32_32x32x32_i8(A[tap], Bhi, ahi, 0, 0, 0);
    }
#pragma unroll
    for (int r = 0; r < 16; ++r) cp[pp][r] = alo[r] + (ahi[r] << 8);
  }

  long long c0[16];
#pragma unroll
  for (int r = 0; r < 16; ++r)
    c0[r] = (long long)cp[0][r] + ((long long)cp[1][r] << 16);

  int n_g = nbase + nloc;
  int oc = rowlane;
  epi_i8<H, W, PADW, COUT, WRITE_T, HAS_RES>(c0, h, oc, pxb + h, y, nloc, n_g,
                                             bias, res, Tout, mout);
}

// ---------------------------------------------------------------------------
// 2x2 average pool + spike (R24 exact integer quarter-count scan).
// ---------------------------------------------------------------------------
__global__ __launch_bounds__(256) void pool_spike(
    const u16* __restrict__ in, u16* __restrict__ out) {
  int idx = blockIdx.x * 256 + threadIdx.x;
  const int total = 128 * 32 * 14 * 14;
  if (idx >= total) return;
  int xx = idx % 14; int t1 = idx / 14;
  int yy = t1 % 14;  int t2 = t1 / 14;
  int c  = t2 % 32;  int n  = t2 / 32;

  const u16* base = in + ((size_t)(n * 32 + c) * 28 + yy * 2) * 28 + xx * 2;
  u32 m00 = base[0], m01 = base[1], m10 = base[28], m11 = base[29];

  u32 q = 0, mo = 0;
#pragma unroll
  for (int t = 0; t < TT; ++t) {
    q += ((m00 >> t) & 1u) + ((m01 >> t) & 1u) + ((m10 >> t) & 1u) +
         ((m11 >> t) & 1u);
    if (q >= 4u) { mo |= (1u << t); q -= 4u; }
  }
  out[idx] = (u16)mo;
}

// ---------------------------------------------------------------------------
// conv1x1 on packed binary input + optional residual + spike
// (R24: f32 accumulation + f64 scan; proven absmax=0.0).
// R27: optional fused T7 write (WRITE_T7): byte (mo>>t)&1 at T7[n][t][f],
// f = o*196+p -- 64 lanes write 64 consecutive bytes per t (coalesced).
// ---------------------------------------------------------------------------
template <int CIN, bool WRITE_T7>
__global__ __launch_bounds__(256) void conv1x1_spike(
    const u16* __restrict__ in, const float* __restrict__ w,
    const float* __restrict__ b, const u16* __restrict__ res,
    u16* __restrict__ out, signed char* __restrict__ T7, int N, int Cout,
    int HW) {
  int idx = blockIdx.x * 256 + threadIdx.x;
  int total = N * Cout * HW;
  if (idx >= total) return;
  int p = idx % HW; int t1 = idx / HW;
  int o = t1 % Cout; int n = t1 / Cout;

  float acc[TT];
  float bv = b[o];
#pragma unroll
  for (int t = 0; t < TT; ++t) acc[t] = bv;

  const u16* inp = in + (size_t)n * CIN * HW + p;
  const float* wo = w + (size_t)o * CIN;
#pragma unroll 4
  for (int c = 0; c < CIN; ++c) {
    u32 m = inp[c * HW];
    float wh = 0.5f * wo[c];
#pragma unroll
    for (int t = 0; t < TT; ++t) {
      u32 hi = (m << (30 - t)) & 0x40000000u;
      acc[t] = fmaf(wh, __uint_as_float(hi), acc[t]);
    }
  }
  if (res) {
    u32 m = res[idx];
#pragma unroll
    for (int t = 0; t < TT; ++t) acc[t] += ((m >> t) & 1u) ? 1.0f : 0.0f;
  }
  // f64 LIF scan over f32 per-step inputs
  double u = 0.0;
  u32 mo = 0;
#pragma unroll
  for (int t = 0; t < TT; ++t) {
    u += (double)acc[t];
    if (u >= 1.0) { mo |= (1u << t); u -= 1.0; }
  }
  if (WRITE_T7) {
    signed char* Tp = T7 + (size_t)n * 16 * 6272 + (o * HW + p);
#pragma unroll
    for (int t = 0; t < TT; ++t)
      Tp[(size_t)t * 6272] = (signed char)((mo >> t) & 1u);
  } else {
    out[idx] = (u16)mo;
  }
}

// ---------------------------------------------------------------------------
// wf1 digit prep, B-frag order (R5-verbatim, 6 planes at 2^45 kept).
// ---------------------------------------------------------------------------
__global__ __launch_bounds__(256) void prep_dense_digits(
    const float* __restrict__ w, signed char* __restrict__ Wd) {
  int linear = blockIdx.x * 256 + threadIdx.x;  // < 301056
  int lane = linear & 63;
  int kc = (linear >> 6) % 196;
  int pg = (linear >> 6) / 196;
  int p = pg % 6, g = pg / 6;
  int col = lane & 31, kh = lane >> 5;
  int o = g * 32 + col, fb = kc * 32 + kh * 16;

  alignas(16) signed char dig[16];
#pragma unroll
  for (int j = 0; j < 16; ++j) {
    double xv = (double)w[(size_t)o * 6272 + fb + j] * 35184372088832.0;
    long long X = (long long)rint(xv);
    unsigned long long Y = (unsigned long long)(X + 0x808080808080LL);
    dig[j] = (signed char)(int)(((Y >> (8 * p)) & 255u) - 128);
  }
  *(i32x4*)(Wd + (size_t)linear * 16) = *(const i32x4*)dig;
}

// ---------------------------------------------------------------------------
// Dense 6272->128, phase A: 16-way K-split partial i8 GEMM (R6/R7-verbatim).
// ---------------------------------------------------------------------------
__global__ __launch_bounds__(256) void dense1_part(
    const signed char* __restrict__ T7, const signed char* __restrict__ Wd,
    long long* __restrict__ Pbuf) {
  __shared__ long long red[3][64][16];
  int tid = threadIdx.x, lane = tid & 63, wid = tid >> 6;
  int bidx = blockIdx.x;
  int Mt = bidx & 63;
  int g = (bidx >> 6) & 3;
  int ks = bidx >> 8;
  int n0 = Mt * 2;
  int nl = (lane >> 4) & 1, tA = lane & 15, kh = lane >> 5;

  const signed char* Arow =
      T7 + ((size_t)(n0 + nl) * 16 + tA) * 6272 + kh * 16;
  const signed char* Bbase = Wd + (size_t)g * 6 * 196 * 1024 + lane * 16;

  int slot = ks * 4 + wid;
  int kc0 = slot * 12 + (slot < 4 ? slot : 4);
  int len = (slot < 4) ? 13 : 12;

  i32x16 acc[6];
#pragma unroll
  for (int p = 0; p < 6; ++p)
#pragma unroll
    for (int r = 0; r < 16; ++r) acc[p][r] = 0;

  for (int kc = kc0; kc < kc0 + len; ++kc) {
    i32x4 Af = *(const i32x4*)(Arow + (size_t)kc * 32);
#pragma unroll
    for (int p = 0; p < 6; ++p) {
      i32x4 Bf = *(const i32x4*)(Bbase + (size_t)(p * 196 + kc) * 1024);
      acc[p] = __builtin_amdgcn_mfma_i32_32x32x32_i8(Af, Bf, acc[p], 0, 0, 0);
    }
  }

  long long cc[16];
#pragma unroll
  for (int r = 0; r < 16; ++r) {
    long long v = 0;
#pragma unroll
    for (int p = 0; p < 6; ++p) v += ((long long)acc[p][r]) << (8 * p);
    cc[r] = v;
  }

  if (wid) {
#pragma unroll
    for (int r = 0; r < 16; ++r) red[wid - 1][lane][r] = cc[r];
  }
  __syncthreads();
  if (wid == 0) {
#pragma unroll
    for (int w2 = 0; w2 < 3; ++w2)
#pragma unroll
      for (int r = 0; r < 16; ++r) cc[r] += red[w2][lane][r];
    long long* P = Pbuf + ((size_t)(ks * 256 + Mt * 4 + g)) * 1024 + lane * 16;
#pragma unroll
    for (int r = 0; r < 16; ++r) P[r] = cc[r];
  }
}

// ---------------------------------------------------------------------------
// Dense phase B: sum 4 ks-partials + exchange + i64 LIF scan (R6/R7-verbatim).
// ---------------------------------------------------------------------------
__global__ __launch_bounds__(64) void dense1_scan(
    const long long* __restrict__ Pbuf, const float* __restrict__ bias,
    u16* __restrict__ out) {
  int bidx = blockIdx.x;  // Mt*4+g, 256
  int lane = threadIdx.x;
  int g = bidx & 3, n0 = (bidx >> 2) * 2;

  long long cc[16];
#pragma unroll
  for (int r = 0; r < 16; ++r) cc[r] = 0;
#pragma unroll
  for (int ks = 0; ks < 4; ++ks) {
    const long long* P =
        Pbuf + ((size_t)(ks * 256 + bidx)) * 1024 + lane * 16;
#pragma unroll
    for (int r = 0; r < 16; ++r) cc[r] += P[r];
  }

  int h = lane >> 5, col = lane & 31;
  long long recv[8];
#pragma unroll
  for (int j = 0; j < 8; ++j) {
    long long send = h ? cc[j] : cc[8 + j];
    recv[j] = shfl_xor64(send, 32);
  }
  long long B45 =
      (long long)rint((double)bias[g * 32 + col] * 35184372088832.0);
  long long u = 0;
  u32 mo = 0;
  const long long TH = 1LL << 45;
#pragma unroll
  for (int t = 0; t < TT; ++t) {
    int lo = (t & 3) + 4 * (t >> 3);
    int sel = (t >> 2) & 1;
    long long own = h ? cc[8 + lo] : cc[lo];
    long long ut = (sel ^ h) ? recv[lo] : own;
    ut += B45;
    u += ut;
    if (u >= TH) { mo |= (1u << t); u -= TH; }
  }
  out[(n0 + h) * 128 + g * 32 + col] = (u16)mo;
}

// ---------------------------------------------------------------------------
// Dense 128 -> 10 + spike + rate (R3-verbatim).
// ---------------------------------------------------------------------------
__global__ __launch_bounds__(64) void dense2_out(
    const u16* __restrict__ in, const float* __restrict__ w,
    const float* __restrict__ b, float* __restrict__ out) {
  int idx = blockIdx.x * 64 + threadIdx.x;
  if (idx >= 1280) return;
  int o = idx % 10;
  int n = idx / 10;

  double acc[TT];
  double bv = (double)b[o];
#pragma unroll
  for (int t = 0; t < TT; ++t) acc[t] = bv;

  const u16* inn = in + (size_t)n * 128;
  const float* wo = w + (size_t)o * 128;
  for (int f = 0; f < 128; ++f) {
    u32 m = inn[f];
    double wv = (double)wo[f];
#pragma unroll
    for (int t = 0; t < TT; ++t) acc[t] += ((m >> t) & 1u) ? wv : 0.0;
  }
  u32 mo = scan_spike(acc);
  out[idx] = (float)__popc(mo) * 0.0625f;
}

// ---------------------------------------------------------------------------
extern "C" void kernel_launch(void* const* d_in, const int* in_sizes, int n_in,
                              void* d_out, int out_size, void* d_ws,
                              size_t ws_size, hipStream_t stream) {
  const float* x   = (const float*)d_in[0];
  const float* w1  = (const float*)d_in[1];
  const float* b1  = (const float*)d_in[2];
  const float* w2  = (const float*)d_in[3];
  const float* b2  = (const float*)d_in[4];
  const float* w3  = (const float*)d_in[5];
  const float* b3  = (const float*)d_in[6];
  const float* w4  = (const float*)d_in[7];
  const float* b4  = (const float*)d_in[8];
  const float* w5  = (const float*)d_in[9];
  const float* b5  = (const float*)d_in[10];
  const float* w6  = (const float*)d_in[11];
  const float* b6  = (const float*)d_in[12];
  const float* wf1 = (const float*)d_in[13];
  const float* bf1 = (const float*)d_in[14];
  const float* wf2 = (const float*)d_in[15];
  const float* bf2 = (const float*)d_in[16];
  float* out = (float*)d_out;

  // Workspace layout (byte offsets). ws_size = 256 MiB. Peak 135,770,112 B.
  char* W = (char*)d_ws;
  u16* s1 = (u16*)(W + 0);               // [128,28,28,32] (R14 relayout)
  u16* s3 = (u16*)(W + 6422528);
  u16* s4 = (u16*)(W + 12845056);        // [128,32,14,14]
  u16* s5 = (u16*)(W + 14450688);        // [128,16,14,14]
  u16* s6 = (u16*)(W + 15253504);
  u16* s7 = (u16*)(W + 16056320);        // (dead since R27; slot kept)
  u16* s8 = (u16*)(W + 17661952);        // [128,128]
  signed char* Wd2 = (signed char*)(W + 17694720);
  signed char* Wd3 = (signed char*)(W + 17750016);
  signed char* T1f = (signed char*)(W + 17805312);  // 58,982,400 B (128 n)
  signed char* T2f = (signed char*)(W + 76787712);  // 58,982,400 B (128 n)
  // Temporal reuse (strictly ordered on the single stream):
  //  - L6: T5c = T1f head (T1f dead after L2), Wd5c = W+34582528.
  //  - L8: T7 = T1f, Wd1 = T2f head (dead after L3), Pbuf = T2f+5,242,880.
  signed char* T5c  = T1f;                             // 16,777,216 B
  signed char* Wd5c = (signed char*)(W + 34582528);    //     36,864 B
  signed char* Wd1 = T2f;                              //  4,816,896 B
  long long*  Pbuf = (long long*)((char*)T2f + 5242880);  // 8,388,608 B
  signed char* T7  = T1f;                              // 12,845,056 B
  (void)s7;

  prep_digits_frag2<<<18, 64, 0, stream>>>(w2, w3, Wd2, Wd3);
  // Border-only zeroing of full-batch T1f/T2f
  zero_borders<<<3712, 256, 0, stream>>>(T1f, T2f);

  // L1: conv3x3 1->32 + spike, fused T1f write, quarter-split (512 blocks)
  conv1_lds<<<512, 448, 0, stream>>>(x, w1, b1, s1, T1f);

  // L2/L3 full batch (i8 MFMA, 4-plane, one-tile-per-thread 512-thr form)
  conv_i8<28, 28, 30, 32, true, false><<<7168, 512, 0, stream>>>(
      T1f, Wd2, b2, nullptr, T2f, nullptr, 0);
  conv_i8<28, 28, 30, 32, false, true><<<7168, 512, 0, stream>>>(
      T2f, Wd3, b3, s1, nullptr, s3, 0);

  // L4: avgpool2 + spike (exact integer)
  pool_spike<<<3136, 256, 0, stream>>>(s3, s4);
  // L5: conv1x1 32->16 + spike (f32 acc + f64 scan)
  conv1x1_spike<32, false><<<1568, 256, 0, stream>>>(
      s4, w4, b4, nullptr, s5, nullptr, 128, 16, 196);
  // L6: conv3x3 16->16 + spike via the proven conv_i8 shape, zero-padded
  // channels (full batch, 1792 blocks)
  hipMemsetAsync(T5c, 0, 16777216, stream);
  prep_digits5c<<<9, 64, 0, stream>>>(w5, Wd5c);
  expand_t5c<<<3136, 256, 0, stream>>>(s5, T5c);
  conv_i8<14, 14, 16, 16, false, false><<<1792, 512, 0, stream>>>(
      T5c, Wd5c, b5, nullptr, nullptr, s6, 0);
  // L7: conv1x1 16->32 + residual(s4) + spike, fused T7 write
  conv1x1_spike<16, true><<<3136, 256, 0, stream>>>(
      s6, w6, b6, s4, nullptr, T7, 128, 32, 196);

  // L8: dense 6272->128 (two-phase i8 MFMA)
  prep_dense_digits<<<1176, 256, 0, stream>>>(wf1, Wd1);
  dense1_part<<<1024, 256, 0, stream>>>(T7, Wd1, Pbuf);
  dense1_scan<<<256, 64, 0, stream>>>(Pbuf, bf1, s8);

  // L9: dense 128->10 + spike + rate
  dense2_out<<<20, 64, 0, stream>>>(s8, wf2, bf2, out);
}

// Round 18
// 449.354 us; speedup vs baseline: 1.0722x; 1.0722x over previous
//
#include <hip/hip_runtime.h>

typedef unsigned short u16;
typedef unsigned int u32;
typedef unsigned long long u64;
typedef __attribute__((ext_vector_type(4))) int i32x4;
typedef __attribute__((ext_vector_type(16))) int i32x16;

#define TT 16
#define Z16 {0, 0, 0, 0, 0, 0, 0, 0, 0, 0, 0, 0, 0, 0, 0, 0}

// ---------------------------------------------------------------------------
// f64 LIF scan (soft reset, THETA=1). R2..R17: absmax=0.0 => order-free,
// margins >> f64 noise.
// ---------------------------------------------------------------------------
__device__ __forceinline__ u32 scan_spike(const double* acc) {
  double u = 0.0;
  u32 m = 0;
#pragma unroll
  for (int t = 0; t < TT; ++t) {
    u += acc[t];
    if (u >= 1.0) { m |= (1u << t); u -= 1.0; }
  }
  return m;
}

__device__ __forceinline__ long long shfl_xor64(long long v, int m) {
  int lo = __shfl_xor((int)(v & 0xffffffffLL), m);
  int hi = __shfl_xor((int)(v >> 32), m);
  return ((long long)hi << 32) | (u32)lo;
}

// ---------------------------------------------------------------------------
// Layer 1: conv3x3 pad1 Cin=1 (R16-proven form, reverted from R17's
// quarter-split which REGRESSED +20us: the 1920-load prologue is amortized
// over 7 tiles at 256 blocks; halving tiles/block doubled per-tile prologue
// cost and beat the 2-blocks/CU latency gain. Retired lever: conv1 grid
// splits in either direction).
// R27 fused T1f interior write kept: bit-identical bytes to the deleted
// expand_masks kernel.
// ---------------------------------------------------------------------------
__device__ __forceinline__ float conv1_fetch(const float* __restrict__ xn,
                                             int y0, int r, int col, int t) {
  int yi = y0 - 1 + r, xi = col - 1;
  if ((unsigned)yi < 28u && (unsigned)xi < 28u)
    return xn[((size_t)(yi * 28 + xi)) * 16 + t];
  return 0.0f;
}

__global__ __launch_bounds__(448) void conv1_lds(
    const float* __restrict__ x, const float* __restrict__ w,
    const float* __restrict__ b, u16* __restrict__ out,
    signed char* __restrict__ T1f) {
  __shared__ float xt[2][4][30][20];
  __shared__ float wl[32][9];

  int blk = blockIdx.x;  // 256: (n, half)
  int n = blk >> 1;
  int half = blk & 1;
  int ypBase = half * 7;
  int tid = threadIdx.x;

  for (int i = tid; i < 288; i += 448) wl[i / 9][i % 9] = w[i];

  // per-thread staging slots (4*30*16 = 1920 values, 448 threads, <=5 each)
  int sr_[5], sc_[5], st_[5];
  bool sok[5];
#pragma unroll
  for (int k = 0; k < 5; ++k) {
    int i = tid + k * 448;
    sok[k] = (i < 1920);
    int ii = sok[k] ? i : 0;
    sr_[k] = ii / 480;
    int rem = ii % 480;
    sc_[k] = rem / 16;
    st_[k] = rem % 16;
  }
  const float* xn = x + (size_t)n * (28 * 28 * 16);

  // thread map: ocg fastest for coalesced mask stores
  int ocg = tid & 7;
  int xx = (tid >> 3) % 28;
  int dy = tid / 224;  // 0 or 1
  int oc0 = ocg * 4;

  // prologue: stage tile 0 into buf 0
  {
    int y0 = ypBase * 2;
#pragma unroll
    for (int k = 0; k < 5; ++k)
      if (sok[k])
        xt[0][sr_[k]][sc_[k]][st_[k]] =
            conv1_fetch(xn, y0, sr_[k], sc_[k], st_[k]);
  }
  __syncthreads();

  float wr[4][9];
#pragma unroll
  for (int j = 0; j < 4; ++j)
#pragma unroll
    for (int ko = 0; ko < 9; ++ko) wr[j][ko] = wl[oc0 + j][ko];
  float bf[4];
#pragma unroll
  for (int j = 0; j < 4; ++j) bf[j] = b[oc0 + j];

  for (int it = 0; it < 7; ++it) {
    int y0 = (ypBase + it) * 2;
    int cur = it & 1;

    // prefetch next tile into regs (latency hides under compute below)
    float pf[5];
    if (it < 6) {
      int y0n = y0 + 2;
#pragma unroll
      for (int k = 0; k < 5; ++k)
        pf[k] = sok[k] ? conv1_fetch(xn, y0n, sr_[k], sc_[k], st_[k]) : 0.0f;
    }

    double u[4] = {0.0, 0.0, 0.0, 0.0};
    u32 m[4] = {0u, 0u, 0u, 0u};

    const float* row0 = &xt[cur][dy + 0][xx][0];
    const float* row1 = &xt[cur][dy + 1][xx][0];
    const float* row2 = &xt[cur][dy + 2][xx][0];

#pragma unroll
    for (int q = 0; q < 4; ++q) {
      float4 xq[9];
#pragma unroll
      for (int kx = 0; kx < 3; ++kx) {
        xq[0 * 3 + kx] = *(const float4*)(row0 + kx * 20 + q * 4);
        xq[1 * 3 + kx] = *(const float4*)(row1 + kx * 20 + q * 4);
        xq[2 * 3 + kx] = *(const float4*)(row2 + kx * 20 + q * 4);
      }
#pragma unroll
      for (int j = 0; j < 4; ++j) {
        float4 s = {0.0f, 0.0f, 0.0f, 0.0f};
#pragma unroll
        for (int ko = 0; ko < 9; ++ko) {
          s.x = fmaf(wr[j][ko], xq[ko].x, s.x);
          s.y = fmaf(wr[j][ko], xq[ko].y, s.y);
          s.z = fmaf(wr[j][ko], xq[ko].z, s.z);
          s.w = fmaf(wr[j][ko], xq[ko].w, s.w);
        }
        float y0f = s.x + bf[j], y1f = s.y + bf[j];
        float y2f = s.z + bf[j], y3f = s.w + bf[j];
        u[j] += (double)y0f;
        if (u[j] >= 1.0) { m[j] |= 1u << (4 * q + 0); u[j] -= 1.0; }
        u[j] += (double)y1f;
        if (u[j] >= 1.0) { m[j] |= 1u << (4 * q + 1); u[j] -= 1.0; }
        u[j] += (double)y2f;
        if (u[j] >= 1.0) { m[j] |= 1u << (4 * q + 2); u[j] -= 1.0; }
        u[j] += (double)y3f;
        if (u[j] >= 1.0) { m[j] |= 1u << (4 * q + 3); u[j] -= 1.0; }
      }
    }

    // coalesced 8B mask store: s1[n][y][x][32c]
    int yo = y0 + dy;
    u64 pk = (u64)(u16)m[0] | ((u64)(u16)m[1] << 16) |
             ((u64)(u16)m[2] << 32) | ((u64)(u16)m[3] << 48);
    *(u64*)(out + ((size_t)(n * 28 + yo) * 28 + xx) * 32 + oc0) = pk;

    // fused T1f interior write (replaces expand_masks)
    {
      signed char* Tp =
          T1f + (((size_t)n * 30 + yo + 1) * 30 + (xx + 1)) * 512 + oc0;
#pragma unroll
      for (int t = 0; t < TT; ++t) {
        u32 val = ((m[0] >> t) & 1u) | (((m[1] >> t) & 1u) << 8) |
                  (((m[2] >> t) & 1u) << 16) | (((m[3] >> t) & 1u) << 24);
        *(u32*)(Tp + t * 32) = val;
      }
    }

    if (it < 6) {
      int nb = (it + 1) & 1;
#pragma unroll
      for (int k = 0; k < 5; ++k)
        if (sok[k]) xt[nb][sr_[k]][sc_[k]][st_[k]] = pf[k];
      __syncthreads();
    }
  }
}

// ---------------------------------------------------------------------------
// Digit prep in MFMA B-frag order for the 32ch 3x3 convs.
// 4 planes at scale 2^29 (R16 numerics; absmax=0.0 held through R5-R17).
// w2+w3 in one launch, grid 18.
// ---------------------------------------------------------------------------
__global__ void prep_digits_frag2(const float* __restrict__ wa,
                                  const float* __restrict__ wb,
                                  signed char* __restrict__ Wda,
                                  signed char* __restrict__ Wdb) {
  int bid = blockIdx.x;  // 18
  const float* w = (bid < 9) ? wa : wb;
  signed char* Wd = (bid < 9) ? Wda : Wdb;
  int tap = bid % 9;
  int lane = threadIdx.x;  // 64
  int oc = lane & 31, kh = lane >> 5;
  for (int j = 0; j < 16; ++j) {
    int c = kh * 16 + j;
    double xv = ldexp((double)w[((size_t)(oc * 32 + c)) * 9 + tap], 29);
    long long X = (long long)rint(xv);
    for (int p = 0; p < 4; ++p) {
      int d = (int)((X + 128) & 255) - 128;
      Wd[((size_t)((p * 9 + tap) * 64 + lane)) * 16 + j] = (signed char)d;
      X = (X - (long long)d) >> 8;
    }
  }
}

// ---------------------------------------------------------------------------
// L6 digit prep for conv_i8<14,14,16,16>: 4 planes at 2^29, oc>=16 and
// c>=16 get zero digits (N/K zero-padding).
// ---------------------------------------------------------------------------
__global__ void prep_digits5c(const float* __restrict__ w,
                              signed char* __restrict__ Wd) {
  int tap = blockIdx.x;    // 9
  int lane = threadIdx.x;  // 64
  int oc = lane & 31, kh = lane >> 5;
  for (int j = 0; j < 16; ++j) {
    long long X = 0;
    if (oc < 16 && kh == 0) {  // c = j < 16 real
      double xv = ldexp((double)w[((size_t)(oc * 16 + j)) * 9 + tap], 29);
      X = (long long)rint(xv);
    }
    for (int p = 0; p < 4; ++p) {
      int d = (int)((X + 128) & 255) - 128;
      Wd[((size_t)((p * 9 + tap) * 64 + lane)) * 16 + j] = (signed char)d;
      X = (X - (long long)d) >> 8;
    }
  }
}

// ---------------------------------------------------------------------------
// Zero only the border sites of full-batch T1f/T2f (x or y in {0,29});
// interiors are fully rewritten (proven R4-R11). 2x7.6 MB instead of 118 MB.
// ---------------------------------------------------------------------------
__global__ __launch_bounds__(256) void zero_borders(
    signed char* __restrict__ T1, signed char* __restrict__ T2) {
  const int PER = 128 * 116 * 32;  // 16B-chunks per buffer
  int idx = blockIdx.x * 256 + threadIdx.x;
  int buf = idx >= PER;
  int r = buf ? idx - PER : idx;
  if (r >= PER) return;
  int c16 = r & 31;
  int site = (r >> 5) % 116;
  int nloc = (r >> 5) / 116;
  int y, x;
  if (site < 30) { y = 0; x = site; }
  else if (site < 60) { y = 29; x = site - 30; }
  else if (site < 88) { x = 0; y = site - 60 + 1; }
  else { x = 29; y = site - 88 + 1; }
  signed char* T = buf ? T2 : T1;
  *(i32x4*)(T + (((size_t)nloc * 30 + y) * 30 + x) * 512 + c16 * 16) =
      (i32x4){0, 0, 0, 0};
}

// ---------------------------------------------------------------------------
// Expand s5 masks (16 ch) -> T5c[n][16][16][16t][32c] in conv_i8 T-format:
// lower 16 c from the proven 32x32 bit-transpose, upper 16 c zeroed by the
// same store. Borders pre-zeroed by memset.
// ---------------------------------------------------------------------------
__global__ __launch_bounds__(256) void expand_t5c(
    const u16* __restrict__ s, signed char* __restrict__ T) {
  int site = blockIdx.x * 8 + (threadIdx.x >> 5);  // 128*14*14
  int gl = threadIdx.x & 31;
  int x = site % 14; int t1 = site / 14;
  int y = t1 % 14;   int n = t1 / 14;

  u32 v = 0;
  if (gl < 16) v = (u32)s[(((size_t)n * 16 + gl) * 14 + y) * 14 + x];
  const u32 MK[5] = {0x0000FFFFu, 0x00FF00FFu, 0x0F0F0F0Fu,
                     0x33333333u, 0x55555555u};
#pragma unroll
  for (int i = 0; i < 5; ++i) {
    int sh = 16 >> i;
    u32 mk = MK[i];
    u32 p = (u32)__shfl_xor((int)v, sh);
    v = ((gl & sh) == 0) ? ((v & mk) | ((p & mk) << sh))
                         : ((v & ~mk) | ((p & ~mk) >> sh));
  }
  if (gl < 16) {
    u32 dw[4];
#pragma unroll
    for (int d = 0; d < 4; ++d) {
      u32 nib = (v >> (4 * d)) & 0xFu;
      dw[d] = (nib * 0x00204081u) & 0x01010101u;
    }
    signed char* Tp =
        T + ((((size_t)n * 16 + y + 1) * 16 + (x + 1))) * 512 + gl * 32;
    *(i32x4*)Tp = (i32x4){(int)dw[0], (int)dw[1], (int)dw[2], (int)dw[3]};
    *(i32x4*)(Tp + 16) = (i32x4){0, 0, 0, 0};  // upper 16 channels zero
  }
}

// ---------------------------------------------------------------------------
// Integer epilogue for 32x32 i8 MFMA C-layout (R4 algebra; scale 2^29).
// Residual gather uses s1's [n][y][x][c] layout (coalesced).
// ---------------------------------------------------------------------------
template <int H, int W, int PADW, int COUT, bool WRITE_T, bool HAS_RES>
__device__ __forceinline__ void epi_i8(long long (&cc)[16], int h, int oc,
                                       int px_out, int y, int nloc, int n_g,
                                       const float* bias,
                                       const u16* __restrict__ res,
                                       signed char* __restrict__ Tout,
                                       u16* __restrict__ mout) {
  long long recv[8];
#pragma unroll
  for (int j = 0; j < 8; ++j) {
    long long send = h ? cc[j] : cc[8 + j];
    recv[j] = shfl_xor64(send, 32);
  }
  long long B29 = 0;
  if (oc < COUT) B29 = (long long)rint((double)bias[oc] * 536870912.0);
  u32 rm = 0;
  if (HAS_RES && px_out < W)
    rm = res[(((size_t)n_g * H + y) * W + px_out) * COUT + oc];
  long long u = 0;
  u32 mo = 0;
  const long long TH = 1LL << 29;
#pragma unroll
  for (int t = 0; t < TT; ++t) {
    int lo = (t & 3) + 4 * (t >> 3);
    int sel = (t >> 2) & 1;
    long long own = h ? cc[8 + lo] : cc[lo];
    long long ut = (sel ^ h) ? recv[lo] : own;
    ut += B29 + (((rm >> t) & 1u) ? TH : 0);
    u += ut;
    if (u >= TH) { mo |= (1u << t); u -= TH; }
  }
  if (px_out < W && oc < COUT) {
    if (WRITE_T) {
      signed char* Tp =
          Tout + (((size_t)nloc * PADW + y + 1) * PADW + px_out + 1) * 512 + oc;
#pragma unroll
      for (int t = 0; t < TT; ++t)
        Tp[t * 32] = (signed char)((mo >> t) & 1u);
    } else {
      mout[(((size_t)n_g * COUT + oc) * H + y) * W + px_out] = (u16)mo;
    }
  }
}

// ---------------------------------------------------------------------------
// conv3x3 via i8 32x32x32 MFMA, 4 digit planes at 2^29.
// R25-proven one-tile-per-thread, 512-thread form (R15/R16: ~93-96us,
// VGPR 56, Occ ~34%, clean traffic). 8 waves/block each owning ONE 2-px
// tile. Retired levers: min-occ>=3 bounds (spills R6/R8); persistent
// blocks (L2 thrash R10/R11).
// ---------------------------------------------------------------------------
template <int H, int W, int PADW, int COUT, bool WRITE_T, bool HAS_RES>
__global__ __launch_bounds__(512, 2) void conv_i8(
    const signed char* __restrict__ Tin, const signed char* __restrict__ Wd,
    const float* __restrict__ bias, const u16* __restrict__ res,
    signed char* __restrict__ Tout, u16* __restrict__ mout, int nbase) {
  constexpr int TILESX = (W + 15) / 16;
  __shared__ signed char WL[4 * 9 * 1024];
  int tid = threadIdx.x;
  for (int j = tid; j < 2304; j += 512)
    ((i32x4*)WL)[j] = ((const i32x4*)Wd)[j];
  __syncthreads();

  int blk = blockIdx.x;
  int xblk = blk % TILESX; int b2 = blk / TILESX;
  int y = b2 % H;          int nloc = b2 / H;
  int lane = tid & 63, wid = tid >> 6;  // wid 0..7
  int h = lane >> 5, rowlane = lane & 31;
  int pxr = rowlane >> 4, tA = rowlane & 15;
  int wtile = wid >> 1, sel = wid & 1;
  int pxb = xblk * 16 + wtile * 4 + sel * 2;  // wave's 2-px tile base

  i32x4 A[9];
  const signed char* Tn = Tin + (size_t)nloc * (PADW * PADW * 512);
#pragma unroll
  for (int ky = 0; ky < 3; ++ky)
#pragma unroll
    for (int kx = 0; kx < 3; ++kx) {
      int tap = ky * 3 + kx;
      int ypad = y + ky;
      int x0 = pxb + pxr + kx;
      if (x0 > PADW - 1) x0 = PADW - 1;
      A[tap] = *(const i32x4*)(Tn + ((size_t)(ypad * PADW + x0)) * 512 +
                               tA * 32 + h * 16);
    }

  i32x16 cp[2];
#pragma unroll
  for (int pp = 0; pp < 2; ++pp) {
    i32x16 alo = Z16, ahi = Z16;
#pragma unroll
    for (int tap = 0; tap < 9; ++tap) {
      i32x4 Blo =
          *(const i32x4*)&WL[((size_t)(((2 * pp) * 9 + tap) * 64 + lane)) * 16];
      i32x4 Bhi = *(const i32x4*)&WL[((size_t)(((2 * pp + 1) * 9 + tap) * 64 +
                                               lane)) * 16];
      alo = __builtin_amdgcn_mfma_i32_32x32x32_i8(A[tap], Blo, alo, 0, 0, 0);
      ahi = __builtin_amdgcn_mfma_i32_32x32x32_i8(A[tap], Bhi, ahi, 0, 0, 0);
    }
#pragma unroll
    for (int r = 0; r < 16; ++r) cp[pp][r] = alo[r] + (ahi[r] << 8);
  }

  long long c0[16];
#pragma unroll
  for (int r = 0; r < 16; ++r)
    c0[r] = (long long)cp[0][r] + ((long long)cp[1][r] << 16);

  int n_g = nbase + nloc;
  int oc = rowlane;
  epi_i8<H, W, PADW, COUT, WRITE_T, HAS_RES>(c0, h, oc, pxb + h, y, nloc, n_g,
                                             bias, res, Tout, mout);
}

// ---------------------------------------------------------------------------
// 2x2 average pool + spike (R24 exact integer quarter-count scan).
// ---------------------------------------------------------------------------
__global__ __launch_bounds__(256) void pool_spike(
    const u16* __restrict__ in, u16* __restrict__ out) {
  int idx = blockIdx.x * 256 + threadIdx.x;
  const int total = 128 * 32 * 14 * 14;
  if (idx >= total) return;
  int xx = idx % 14; int t1 = idx / 14;
  int yy = t1 % 14;  int t2 = t1 / 14;
  int c  = t2 % 32;  int n  = t2 / 32;

  const u16* base = in + ((size_t)(n * 32 + c) * 28 + yy * 2) * 28 + xx * 2;
  u32 m00 = base[0], m01 = base[1], m10 = base[28], m11 = base[29];

  u32 q = 0, mo = 0;
#pragma unroll
  for (int t = 0; t < TT; ++t) {
    q += ((m00 >> t) & 1u) + ((m01 >> t) & 1u) + ((m10 >> t) & 1u) +
         ((m11 >> t) & 1u);
    if (q >= 4u) { mo |= (1u << t); q -= 4u; }
  }
  out[idx] = (u16)mo;
}

// ---------------------------------------------------------------------------
// conv1x1 on packed binary input + optional residual + spike
// (R24: f32 accumulation + f64 scan; proven absmax=0.0).
// R27: optional fused T7 write (WRITE_T7): byte (mo>>t)&1 at T7[n][t][f],
// f = o*196+p -- 64 lanes write 64 consecutive bytes per t (coalesced).
// ---------------------------------------------------------------------------
template <int CIN, bool WRITE_T7>
__global__ __launch_bounds__(256) void conv1x1_spike(
    const u16* __restrict__ in, const float* __restrict__ w,
    const float* __restrict__ b, const u16* __restrict__ res,
    u16* __restrict__ out, signed char* __restrict__ T7, int N, int Cout,
    int HW) {
  int idx = blockIdx.x * 256 + threadIdx.x;
  int total = N * Cout * HW;
  if (idx >= total) return;
  int p = idx % HW; int t1 = idx / HW;
  int o = t1 % Cout; int n = t1 / Cout;

  float acc[TT];
  float bv = b[o];
#pragma unroll
  for (int t = 0; t < TT; ++t) acc[t] = bv;

  const u16* inp = in + (size_t)n * CIN * HW + p;
  const float* wo = w + (size_t)o * CIN;
#pragma unroll 4
  for (int c = 0; c < CIN; ++c) {
    u32 m = inp[c * HW];
    float wh = 0.5f * wo[c];
#pragma unroll
    for (int t = 0; t < TT; ++t) {
      u32 hi = (m << (30 - t)) & 0x40000000u;
      acc[t] = fmaf(wh, __uint_as_float(hi), acc[t]);
    }
  }
  if (res) {
    u32 m = res[idx];
#pragma unroll
    for (int t = 0; t < TT; ++t) acc[t] += ((m >> t) & 1u) ? 1.0f : 0.0f;
  }
  // f64 LIF scan over f32 per-step inputs
  double u = 0.0;
  u32 mo = 0;
#pragma unroll
  for (int t = 0; t < TT; ++t) {
    u += (double)acc[t];
    if (u >= 1.0) { mo |= (1u << t); u -= 1.0; }
  }
  if (WRITE_T7) {
    signed char* Tp = T7 + (size_t)n * 16 * 6272 + (o * HW + p);
#pragma unroll
    for (int t = 0; t < TT; ++t)
      Tp[(size_t)t * 6272] = (signed char)((mo >> t) & 1u);
  } else {
    out[idx] = (u16)mo;
  }
}

// ---------------------------------------------------------------------------
// wf1 digit prep, B-frag order (R5-verbatim, 6 planes at 2^45 kept).
// ---------------------------------------------------------------------------
__global__ __launch_bounds__(256) void prep_dense_digits(
    const float* __restrict__ w, signed char* __restrict__ Wd) {
  int linear = blockIdx.x * 256 + threadIdx.x;  // < 301056
  int lane = linear & 63;
  int kc = (linear >> 6) % 196;
  int pg = (linear >> 6) / 196;
  int p = pg % 6, g = pg / 6;
  int col = lane & 31, kh = lane >> 5;
  int o = g * 32 + col, fb = kc * 32 + kh * 16;

  alignas(16) signed char dig[16];
#pragma unroll
  for (int j = 0; j < 16; ++j) {
    double xv = (double)w[(size_t)o * 6272 + fb + j] * 35184372088832.0;
    long long X = (long long)rint(xv);
    unsigned long long Y = (unsigned long long)(X + 0x808080808080LL);
    dig[j] = (signed char)(int)(((Y >> (8 * p)) & 255u) - 128);
  }
  *(i32x4*)(Wd + (size_t)linear * 16) = *(const i32x4*)dig;
}

// ---------------------------------------------------------------------------
// Dense 6272->128, phase A: 16-way K-split partial i8 GEMM (R6/R7-verbatim).
// ---------------------------------------------------------------------------
__global__ __launch_bounds__(256) void dense1_part(
    const signed char* __restrict__ T7, const signed char* __restrict__ Wd,
    long long* __restrict__ Pbuf) {
  __shared__ long long red[3][64][16];
  int tid = threadIdx.x, lane = tid & 63, wid = tid >> 6;
  int bidx = blockIdx.x;
  int Mt = bidx & 63;
  int g = (bidx >> 6) & 3;
  int ks = bidx >> 8;
  int n0 = Mt * 2;
  int nl = (lane >> 4) & 1, tA = lane & 15, kh = lane >> 5;

  const signed char* Arow =
      T7 + ((size_t)(n0 + nl) * 16 + tA) * 6272 + kh * 16;
  const signed char* Bbase = Wd + (size_t)g * 6 * 196 * 1024 + lane * 16;

  int slot = ks * 4 + wid;
  int kc0 = slot * 12 + (slot < 4 ? slot : 4);
  int len = (slot < 4) ? 13 : 12;

  i32x16 acc[6];
#pragma unroll
  for (int p = 0; p < 6; ++p)
#pragma unroll
    for (int r = 0; r < 16; ++r) acc[p][r] = 0;

  for (int kc = kc0; kc < kc0 + len; ++kc) {
    i32x4 Af = *(const i32x4*)(Arow + (size_t)kc * 32);
#pragma unroll
    for (int p = 0; p < 6; ++p) {
      i32x4 Bf = *(const i32x4*)(Bbase + (size_t)(p * 196 + kc) * 1024);
      acc[p] = __builtin_amdgcn_mfma_i32_32x32x32_i8(Af, Bf, acc[p], 0, 0, 0);
    }
  }

  long long cc[16];
#pragma unroll
  for (int r = 0; r < 16; ++r) {
    long long v = 0;
#pragma unroll
    for (int p = 0; p < 6; ++p) v += ((long long)acc[p][r]) << (8 * p);
    cc[r] = v;
  }

  if (wid) {
#pragma unroll
    for (int r = 0; r < 16; ++r) red[wid - 1][lane][r] = cc[r];
  }
  __syncthreads();
  if (wid == 0) {
#pragma unroll
    for (int w2 = 0; w2 < 3; ++w2)
#pragma unroll
      for (int r = 0; r < 16; ++r) cc[r] += red[w2][lane][r];
    long long* P = Pbuf + ((size_t)(ks * 256 + Mt * 4 + g)) * 1024 + lane * 16;
#pragma unroll
    for (int r = 0; r < 16; ++r) P[r] = cc[r];
  }
}

// ---------------------------------------------------------------------------
// Dense phase B: sum 4 ks-partials + exchange + i64 LIF scan (R6/R7-verbatim).
// ---------------------------------------------------------------------------
__global__ __launch_bounds__(64) void dense1_scan(
    const long long* __restrict__ Pbuf, const float* __restrict__ bias,
    u16* __restrict__ out) {
  int bidx = blockIdx.x;  // Mt*4+g, 256
  int lane = threadIdx.x;
  int g = bidx & 3, n0 = (bidx >> 2) * 2;

  long long cc[16];
#pragma unroll
  for (int r = 0; r < 16; ++r) cc[r] = 0;
#pragma unroll
  for (int ks = 0; ks < 4; ++ks) {
    const long long* P =
        Pbuf + ((size_t)(ks * 256 + bidx)) * 1024 + lane * 16;
#pragma unroll
    for (int r = 0; r < 16; ++r) cc[r] += P[r];
  }

  int h = lane >> 5, col = lane & 31;
  long long recv[8];
#pragma unroll
  for (int j = 0; j < 8; ++j) {
    long long send = h ? cc[j] : cc[8 + j];
    recv[j] = shfl_xor64(send, 32);
  }
  long long B45 =
      (long long)rint((double)bias[g * 32 + col] * 35184372088832.0);
  long long u = 0;
  u32 mo = 0;
  const long long TH = 1LL << 45;
#pragma unroll
  for (int t = 0; t < TT; ++t) {
    int lo = (t & 3) + 4 * (t >> 3);
    int sel = (t >> 2) & 1;
    long long own = h ? cc[8 + lo] : cc[lo];
    long long ut = (sel ^ h) ? recv[lo] : own;
    ut += B45;
    u += ut;
    if (u >= TH) { mo |= (1u << t); u -= TH; }
  }
  out[(n0 + h) * 128 + g * 32 + col] = (u16)mo;
}

// ---------------------------------------------------------------------------
// Dense 128 -> 10 + spike + rate (R3-verbatim).
// ---------------------------------------------------------------------------
__global__ __launch_bounds__(64) void dense2_out(
    const u16* __restrict__ in, const float* __restrict__ w,
    const float* __restrict__ b, float* __restrict__ out) {
  int idx = blockIdx.x * 64 + threadIdx.x;
  if (idx >= 1280) return;
  int o = idx % 10;
  int n = idx / 10;

  double acc[TT];
  double bv = (double)b[o];
#pragma unroll
  for (int t = 0; t < TT; ++t) acc[t] = bv;

  const u16* inn = in + (size_t)n * 128;
  const float* wo = w + (size_t)o * 128;
  for (int f = 0; f < 128; ++f) {
    u32 m = inn[f];
    double wv = (double)wo[f];
#pragma unroll
    for (int t = 0; t < TT; ++t) acc[t] += ((m >> t) & 1u) ? wv : 0.0;
  }
  u32 mo = scan_spike(acc);
  out[idx] = (float)__popc(mo) * 0.0625f;
}

// ---------------------------------------------------------------------------
extern "C" void kernel_launch(void* const* d_in, const int* in_sizes, int n_in,
                              void* d_out, int out_size, void* d_ws,
                              size_t ws_size, hipStream_t stream) {
  const float* x   = (const float*)d_in[0];
  const float* w1  = (const float*)d_in[1];
  const float* b1  = (const float*)d_in[2];
  const float* w2  = (const float*)d_in[3];
  const float* b2  = (const float*)d_in[4];
  const float* w3  = (const float*)d_in[5];
  const float* b3  = (const float*)d_in[6];
  const float* w4  = (const float*)d_in[7];
  const float* b4  = (const float*)d_in[8];
  const float* w5  = (const float*)d_in[9];
  const float* b5  = (const float*)d_in[10];
  const float* w6  = (const float*)d_in[11];
  const float* b6  = (const float*)d_in[12];
  const float* wf1 = (const float*)d_in[13];
  const float* bf1 = (const float*)d_in[14];
  const float* wf2 = (const float*)d_in[15];
  const float* bf2 = (const float*)d_in[16];
  float* out = (float*)d_out;

  // Workspace layout (byte offsets). ws_size = 256 MiB. Peak 135,770,112 B.
  char* W = (char*)d_ws;
  u16* s1 = (u16*)(W + 0);               // [128,28,28,32] (R14 relayout)
  u16* s3 = (u16*)(W + 6422528);
  u16* s4 = (u16*)(W + 12845056);        // [128,32,14,14]
  u16* s5 = (u16*)(W + 14450688);        // [128,16,14,14]
  u16* s6 = (u16*)(W + 15253504);
  u16* s7 = (u16*)(W + 16056320);        // (dead since R27; slot kept)
  u16* s8 = (u16*)(W + 17661952);        // [128,128]
  signed char* Wd2 = (signed char*)(W + 17694720);
  signed char* Wd3 = (signed char*)(W + 17750016);
  signed char* T1f = (signed char*)(W + 17805312);  // 58,982,400 B (128 n)
  signed char* T2f = (signed char*)(W + 76787712);  // 58,982,400 B (128 n)
  // Temporal reuse (strictly ordered on the single stream):
  //  - L6: T5c = T1f head (T1f dead after L2), Wd5c = W+34582528.
  //  - L8: T7 = T1f, Wd1 = T2f head (dead after L3), Pbuf = T2f+5,242,880.
  signed char* T5c  = T1f;                             // 16,777,216 B
  signed char* Wd5c = (signed char*)(W + 34582528);    //     36,864 B
  signed char* Wd1 = T2f;                              //  4,816,896 B
  long long*  Pbuf = (long long*)((char*)T2f + 5242880);  // 8,388,608 B
  signed char* T7  = T1f;                              // 12,845,056 B
  (void)s7;

  prep_digits_frag2<<<18, 64, 0, stream>>>(w2, w3, Wd2, Wd3);
  // Border-only zeroing of full-batch T1f/T2f
  zero_borders<<<3712, 256, 0, stream>>>(T1f, T2f);

  // L1: conv3x3 1->32 + spike, fused T1f write (R16-proven 256-block form)
  conv1_lds<<<256, 448, 0, stream>>>(x, w1, b1, s1, T1f);

  // L2/L3 full batch (i8 MFMA, 4-plane, one-tile-per-thread 512-thr form)
  conv_i8<28, 28, 30, 32, true, false><<<7168, 512, 0, stream>>>(
      T1f, Wd2, b2, nullptr, T2f, nullptr, 0);
  conv_i8<28, 28, 30, 32, false, true><<<7168, 512, 0, stream>>>(
      T2f, Wd3, b3, s1, nullptr, s3, 0);

  // L4: avgpool2 + spike (exact integer)
  pool_spike<<<3136, 256, 0, stream>>>(s3, s4);
  // L5: conv1x1 32->16 + spike (f32 acc + f64 scan)
  conv1x1_spike<32, false><<<1568, 256, 0, stream>>>(
      s4, w4, b4, nullptr, s5, nullptr, 128, 16, 196);
  // L6: conv3x3 16->16 + spike via the proven conv_i8 shape, zero-padded
  // channels (full batch, 1792 blocks)
  hipMemsetAsync(T5c, 0, 16777216, stream);
  prep_digits5c<<<9, 64, 0, stream>>>(w5, Wd5c);
  expand_t5c<<<3136, 256, 0, stream>>>(s5, T5c);
  conv_i8<14, 14, 16, 16, false, false><<<1792, 512, 0, stream>>>(
      T5c, Wd5c, b5, nullptr, nullptr, s6, 0);
  // L7: conv1x1 16->32 + residual(s4) + spike, fused T7 write
  conv1x1_spike<16, true><<<3136, 256, 0, stream>>>(
      s6, w6, b6, s4, nullptr, T7, 128, 32, 196);

  // L8: dense 6272->128 (two-phase i8 MFMA)
  prep_dense_digits<<<1176, 256, 0, stream>>>(wf1, Wd1);
  dense1_part<<<1024, 256, 0, stream>>>(T7, Wd1, Pbuf);
  dense1_scan<<<256, 64, 0, stream>>>(Pbuf, bf1, s8);

  // L9: dense 128->10 + spike + rate
  dense2_out<<<20, 64, 0, stream>>>(s8, wf2, bf2, out);
}